// Round 3
// baseline (350.109 us; speedup 1.0000x reference)
//
#include <hip/hip_runtime.h>
#include <hip/hip_bf16.h>

// Shapes: N=128, C_IN=C_OUT=64, T=128, V=25, S=3, R=8
// ws layout (bytes):
//   adjfrag (bf16 B-frag) [3][128][64][2 ut][64 lane][8 j]  @ 0           50,331,648
//   w3frag  (bf16 B-frag) [3][2 kb][4 ot][64 lane][8 j]     @ 50,331,648      24,576
//   xT      (bf16) [128][3200 tv][64 c]                     @ 50,356,224  52,428,800
//   xbar    (f32)  [128][64][25]                            @ 102,785,024    819,200
//   partials(f32)  [64 o][2 stat][1024 blk]                 @ 103,604,224    524,288
//   stats   (f32)  [128]                                    @ 104,128,512        512
//   coef    (f32)  [64][2]                                  @ 104,129,024        512

typedef __attribute__((ext_vector_type(8))) short bf16x8;
typedef __attribute__((ext_vector_type(4))) float f32x4;

__device__ inline unsigned short f2bf(float f) {
    union { float f; unsigned int u; } x; x.f = f;
    unsigned int u = x.u;
    return (unsigned short)((u + 0x7FFFu + ((u >> 16) & 1u)) >> 16);
}

__global__ void k_zero(float* xbar) {
    int i = blockIdx.x * 256 + threadIdx.x;
    if (i < 204800) xbar[i] = 0.f;
}

// ---- W3 -> B-fragment-linear bf16 ----
__global__ void k_w3prep(const float* __restrict__ W3, unsigned short* __restrict__ w3f) {
    int g = blockIdx.x * 512 + threadIdx.x;          // 0..1535
    if (g >= 1536) return;
    int grp = g >> 6, lane = g & 63;
    int s = grp >> 3, kb = (grp >> 2) & 1, ot = grp & 3;
    int o = ot * 16 + (lane & 15);
    int c0 = kb * 32 + (lane >> 4) * 8;
    const float* src = W3 + (s * 64 + o) * 64 + c0;
    unsigned int p[4];
#pragma unroll
    for (int e = 0; e < 4; e++)
        p[e] = (unsigned int)f2bf(src[2 * e]) | ((unsigned int)f2bf(src[2 * e + 1]) << 16);
    uint4 v; v.x = p[0]; v.y = p[1]; v.z = p[2]; v.w = p[3];
    *(uint4*)(w3f + (grp * 64 + lane) * 8) = v;
}

// ---- k_prep: one pass over x -> xbar partials (atomic) + transposed bf16 xT ----
__launch_bounds__(256)
__global__ void k_prep(const float* __restrict__ x, float* __restrict__ xbar,
                       unsigned short* __restrict__ xT) {
    __shared__ float xl[64 * 401];          // pad 401 -> conflict-free column reads
    int bid = blockIdx.x;                   // 0..1023
    int n = bid >> 3, tc = bid & 7;
    int tid = threadIdx.x;
    const float* xs = x + (size_t)n * 204800 + tc * 400;
    for (int idx = tid; idx < 6400; idx += 256) {
        int c = idx / 100, r4 = idx - c * 100;
        float4 q = *(const float4*)(xs + c * 3200 + r4 * 4);
        float* d = &xl[c * 401 + r4 * 4];
        d[0] = q.x; d[1] = q.y; d[2] = q.z; d[3] = q.w;
    }
    __syncthreads();
    for (int i = tid; i < 1600; i += 256) {
        int c = i / 25, v = i - c * 25;
        float ssum = 0.f;
#pragma unroll
        for (int t = 0; t < 16; t++) ssum += xl[c * 401 + t * 25 + v];
        atomicAdd(&xbar[n * 1600 + i], ssum * (1.f / 128.f));
    }
    unsigned int* out = (unsigned int*)xT + (size_t)n * 102400 + tc * 12800;
    for (int j = tid; j < 12800; j += 256) {
        int cp = j & 31, tv = j >> 5;
        unsigned int lo = f2bf(xl[(2 * cp) * 401 + tv]);
        unsigned int hi = f2bf(xl[(2 * cp + 1) * 401 + tv]);
        out[tv * 32 + cp] = lo | (hi << 16);
    }
}

// ---- K2: adj in B-fragment-linear bf16, zero-padded for u>=25 / v>=25 ----
__global__ void k_adj(const float* __restrict__ xbar,
                      const float* __restrict__ W1, const float* __restrict__ b1,
                      const float* __restrict__ W2, const float* __restrict__ b2,
                      const float* __restrict__ W4, const float* __restrict__ b4,
                      const float* __restrict__ PA, const float* __restrict__ alpha,
                      unsigned short* __restrict__ adjfrag) {
    int sb = blockIdx.x;          // 0..383
    int s = sb >> 7, n = sb & 127;
    __shared__ float xb[1600], w1l[512], w2l[512], w4l[512], b4l[64], pal[625];
    __shared__ float x1l[200], x2l[200];
    __shared__ float dt[8][25][28];
    int tid = threadIdx.x;        // 256
    for (int i = tid; i < 1600; i += 256) xb[i] = xbar[n * 1600 + i];
    for (int i = tid; i < 512; i += 256) {
        w1l[i] = W1[s * 512 + i];
        w2l[i] = W2[s * 512 + i];
        w4l[i] = W4[s * 512 + i];
    }
    if (tid < 64) b4l[tid] = b4[s * 64 + tid];
    for (int i = tid; i < 625; i += 256) pal[i] = PA[s * 625 + i];
    __syncthreads();
    if (tid < 200) {
        int r = tid / 25, v = tid % 25;
        float a1 = b1[s * 8 + r], a2 = b2[s * 8 + r];
        for (int c = 0; c < 64; c++) {
            float xv = xb[c * 25 + v];
            a1 += w1l[r * 64 + c] * xv;
            a2 += w2l[r * 64 + c] * xv;
        }
        x1l[tid] = a1;
        x2l[tid] = a2;
    }
    __syncthreads();
    for (int i = tid; i < 5000; i += 256) {
        int r = i / 625, uv = i % 625, u = uv / 25, v = uv % 25;
        dt[r][u][v] = tanhf(x1l[r * 25 + u] - x2l[r * 25 + v]);
    }
    for (int i = tid; i < 600; i += 256) {
        int r = i / 75, rem = i % 75, u = rem / 3, v = 25 + rem % 3;
        dt[r][u][v] = 0.f;
    }
    __syncthreads();

    int f = tid * 4;
    int lane = (f >> 3) & 63;
    int j0 = f & 7;
    int u = ((f >> 9) << 4) + (lane & 15);
    int v0 = ((lane >> 4) << 3) + j0;
    bool uok = (u < 25);
    float4 dr[8];
    if (uok && v0 < 28) {
#pragma unroll
        for (int r = 0; r < 8; r++) dr[r] = *(const float4*)&dt[r][u][v0];
    } else {
#pragma unroll
        for (int r = 0; r < 8; r++) { dr[r].x = dr[r].y = dr[r].z = dr[r].w = 0.f; }
    }
    float al = alpha[s];
    bool vok[4]; float pae[4];
#pragma unroll
    for (int e = 0; e < 4; e++) {
        int v = v0 + e;
        vok[e] = uok && (v < 25);
        pae[e] = vok[e] ? pal[u * 25 + v] : 0.f;
    }
    unsigned short* outp = adjfrag + ((size_t)(s * 128 + n)) * 65536 + f;
    for (int o = 0; o < 64; o++) {
        float b4o = b4l[o];
        unsigned short q[4];
#pragma unroll
        for (int e = 0; e < 4; e++) {
            float acc = 0.f;
            if (vok[e]) {
                float dot = b4o;
#pragma unroll
                for (int r = 0; r < 8; r++) {
                    float dv = (e == 0) ? dr[r].x : (e == 1) ? dr[r].y : (e == 2) ? dr[r].z : dr[r].w;
                    dot += w4l[o * 8 + r] * dv;
                }
                acc = dot * al + pae[e];
            }
            q[e] = f2bf(acc);
        }
        uint2 pk = make_uint2((unsigned int)q[0] | ((unsigned int)q[1] << 16),
                              (unsigned int)q[2] | ((unsigned int)q[3] << 16));
        *(uint2*)(outp + o * 1024) = pk;
    }
}

// ---- K3: MFMA main. PHASE 0: BN partial sums only. PHASE 1: fused BN+res+relu out ----
template<int PHASE>
__launch_bounds__(512, 2)
__global__ void k_main(const unsigned short* __restrict__ xT, const float* __restrict__ b3g,
                       const unsigned short* __restrict__ w3f,
                       const unsigned short* __restrict__ adjf,
                       const float* __restrict__ x, float* __restrict__ outp,
                       float* __restrict__ partials, const float* __restrict__ coef) {
    __shared__ unsigned short x3l[64 * 648];   // [o][t*40+v], 16B-aligned rows
    __shared__ float b3l[192];
    __shared__ float coefl[128];

    int bid = blockIdx.x;                      // 0..1023
    int xcd = bid & 7, j = bid >> 3;
    int tc = j & 7, n = (xcd << 4) | (j >> 3);
    int tid = threadIdx.x;
    int w = tid >> 6, lane = tid & 63, l15 = lane & 15, l4 = lane >> 4;

    if (tid < 192) b3l[tid] = b3g[tid];
    if (PHASE == 1 && tid < 128) coefl[tid] = coef[tid];
    __syncthreads();

    const unsigned short* xTn = xT + ((size_t)n * 3200 + tc * 400) * 64;
    f32x4 zero4 = {0.f, 0.f, 0.f, 0.f};
    bf16x8 zerob = {0, 0, 0, 0, 0, 0, 0, 0};
    f32x4 yacc[16];
#pragma unroll
    for (int i = 0; i < 16; i++) yacc[i] = zero4;

    int nt = w & 3, mfbase = w >> 2;

    for (int s = 0; s < 3; s++) {
        // prefetch adj B-frags for stage 2 (overlaps all of stage 1)
        bf16x8 badj[16];
        const unsigned short* ab = adjf + ((size_t)(s * 128 + n)) * 65536;
#pragma unroll
        for (int k = 0; k < 8; k++) {
            int o = w * 8 + k;
            badj[2 * k]     = *(const bf16x8*)(ab + ((size_t)o * 2 + 0) * 512 + lane * 8);
            badj[2 * k + 1] = *(const bf16x8*)(ab + ((size_t)o * 2 + 1) * 512 + lane * 8);
        }
        // ---- stage 1: x3 = W3.x + b3 -> LDS ----
        bf16x8 bw0 = *(const bf16x8*)(w3f + ((s * 8 + nt) * 64 + lane) * 8);
        bf16x8 bw1 = *(const bf16x8*)(w3f + ((s * 8 + 4 + nt) * 64 + lane) * 8);
        float bias = b3l[s * 64 + nt * 16 + l15];
#pragma unroll 4
        for (int i = 0; i < 16; i++) {
            int mf = mfbase + 2 * i;
            int m = mf * 16 + l15;
            int t = m >> 5, v = m & 31;
            bf16x8 a0, a1;
            if (v < 25) {
                const unsigned short* ap = xTn + (size_t)(t * 25 + v) * 64 + l4 * 8;
                a0 = *(const bf16x8*)ap;
                a1 = *(const bf16x8*)(ap + 32);
            } else {
                a0 = zerob; a1 = zerob;
            }
            f32x4 d = zero4;
            d = __builtin_amdgcn_mfma_f32_16x16x32_bf16(a0, bw0, d, 0, 0, 0);
            d = __builtin_amdgcn_mfma_f32_16x16x32_bf16(a1, bw1, d, 0, 0, 0);
            int o = nt * 16 + l15;
            int tt_ = mf >> 1, v0 = (mf & 1) * 16 + l4 * 4;
            unsigned int p0 = (unsigned int)f2bf(d[0] + bias) | ((unsigned int)f2bf(d[1] + bias) << 16);
            unsigned int p1 = (unsigned int)f2bf(d[2] + bias) | ((unsigned int)f2bf(d[3] + bias) << 16);
            *(uint2*)(&x3l[o * 648 + tt_ * 40 + v0]) = make_uint2(p0, p1);
        }
        __syncthreads();
        // ---- stage 2: y += x3 . adjT ----
#pragma unroll
        for (int k = 0; k < 8; k++) {
            int o = w * 8 + k;
            bf16x8 a = *(const bf16x8*)(&x3l[o * 648 + l15 * 40 + l4 * 8]);
            yacc[2 * k]     = __builtin_amdgcn_mfma_f32_16x16x32_bf16(a, badj[2 * k],     yacc[2 * k],     0, 0, 0);
            yacc[2 * k + 1] = __builtin_amdgcn_mfma_f32_16x16x32_bf16(a, badj[2 * k + 1], yacc[2 * k + 1], 0, 0, 0);
        }
        __syncthreads();
    }

    if (PHASE == 0) {
        // BN partial sums (pad-u cols are exact zero via adj zero-pad)
#pragma unroll
        for (int k = 0; k < 8; k++) {
            int o = w * 8 + k;
            float s1 = 0.f, s2 = 0.f;
#pragma unroll
            for (int ut = 0; ut < 2; ut++) {
                f32x4 d = yacc[2 * k + ut];
#pragma unroll
                for (int r = 0; r < 4; r++) {
                    float val = d[r];
                    s1 += val; s2 += val * val;
                }
            }
#pragma unroll
            for (int off = 1; off < 64; off <<= 1) {
                s1 += __shfl_xor(s1, off);
                s2 += __shfl_xor(s2, off);
            }
            if (lane == 0) {
                partials[((size_t)o * 2 + 0) * 1024 + bid] = s1;
                partials[((size_t)o * 2 + 1) * 1024 + bid] = s2;
            }
        }
    } else {
#pragma unroll
        for (int k = 0; k < 8; k++) {
            int o = w * 8 + k;
            float sc = coefl[o * 2], sh = coefl[o * 2 + 1];
#pragma unroll
            for (int ut = 0; ut < 2; ut++) {
                int u = ut * 16 + l15;
                f32x4 d = yacc[2 * k + ut];
                if (u < 25) {
#pragma unroll
                    for (int r = 0; r < 4; r++) {
                        int tg = tc * 16 + l4 * 4 + r;
                        size_t idx = (((size_t)n * 64 + o) * 128 + tg) * 25 + u;
                        outp[idx] = fmaxf(d[r] * sc + sh + x[idx], 0.f);
                    }
                }
            }
        }
    }
}

// ---- reduce partials ----
__global__ void k_reduce(const float* __restrict__ partials, float* __restrict__ stats) {
    int row = blockIdx.x;                    // 0..127
    float a = 0.f;
    for (int i = threadIdx.x; i < 1024; i += 256) a += partials[row * 1024 + i];
    for (int off = 32; off; off >>= 1) a += __shfl_down(a, off);
    __shared__ float r4[4];
    int wv = threadIdx.x >> 6, ln = threadIdx.x & 63;
    if (ln == 0) r4[wv] = a;
    __syncthreads();
    if (threadIdx.x == 0) stats[row] = r4[0] + r4[1] + r4[2] + r4[3];
}

__global__ void k_coef(const float* __restrict__ stats, const float* __restrict__ bnw,
                       const float* __restrict__ bnb, float* __restrict__ coef) {
    int o = threadIdx.x;
    if (o < 64) {
        const float inv = 1.f / 409600.f;
        float mean = stats[o * 2] * inv;
        float var = stats[o * 2 + 1] * inv - mean * mean;
        float sc = bnw[o] * rsqrtf(var + 1e-5f);
        coef[o * 2] = sc;
        coef[o * 2 + 1] = bnb[o] - mean * sc;
    }
}

extern "C" void kernel_launch(void* const* d_in, const int* in_sizes, int n_in,
                              void* d_out, int out_size, void* d_ws, size_t ws_size,
                              hipStream_t stream) {
    const float* x    = (const float*)d_in[0];
    const float* W1   = (const float*)d_in[1];
    const float* b1   = (const float*)d_in[2];
    const float* W2   = (const float*)d_in[3];
    const float* b2   = (const float*)d_in[4];
    const float* W3   = (const float*)d_in[5];
    const float* b3   = (const float*)d_in[6];
    const float* W4   = (const float*)d_in[7];
    const float* b4   = (const float*)d_in[8];
    const float* PA   = (const float*)d_in[9];
    const float* alpha= (const float*)d_in[10];
    const float* bnw  = (const float*)d_in[11];
    const float* bnb  = (const float*)d_in[12];

    char* wsb = (char*)d_ws;
    unsigned short* adjfrag = (unsigned short*)wsb;
    unsigned short* w3frag  = (unsigned short*)(wsb + 50331648);
    unsigned short* xT      = (unsigned short*)(wsb + 50356224);
    float* xbar     = (float*)(wsb + 102785024);
    float* partials = (float*)(wsb + 103604224);
    float* stats    = (float*)(wsb + 104128512);
    float* coef     = (float*)(wsb + 104129024);
    float* outp     = (float*)d_out;

    hipLaunchKernelGGL(k_zero, dim3(800), dim3(256), 0, stream, xbar);
    hipLaunchKernelGGL(k_w3prep, dim3(3), dim3(512), 0, stream, W3, w3frag);
    hipLaunchKernelGGL(k_prep, dim3(1024), dim3(256), 0, stream, x, xbar, xT);
    hipLaunchKernelGGL(k_adj, dim3(384), dim3(256), 0, stream,
                       xbar, W1, b1, W2, b2, W4, b4, PA, alpha, adjfrag);
    hipLaunchKernelGGL((k_main<0>), dim3(1024), dim3(512), 0, stream,
                       xT, b3, w3frag, adjfrag, x, outp, partials, coef);
    hipLaunchKernelGGL(k_reduce, dim3(128), dim3(256), 0, stream, partials, stats);
    hipLaunchKernelGGL(k_coef, dim3(1), dim3(64), 0, stream, stats, bnw, bnb, coef);
    hipLaunchKernelGGL((k_main<1>), dim3(1024), dim3(512), 0, stream,
                       xT, b3, w3frag, adjfrag, x, outp, partials, coef);
}